// Round 14
// baseline (204.967 us; speedup 1.0000x reference)
//
#include <hip/hip_runtime.h>
#include <hip/hip_bf16.h>

#define N_NODES   50000
#define N_EDGES   640000
#define NODE_DIM  16
#define HIDDEN    128
#define LATENT    64
#define MAX_NODES 100
#define NUM_GRAPHS 256

typedef unsigned short ushort_t;
typedef unsigned int   uint_t;
typedef short  short8 __attribute__((ext_vector_type(8)));   // 8 bf16 = 4 VGPR
typedef float  f32x4  __attribute__((ext_vector_type(4)));

__device__ __forceinline__ float bf2f(ushort_t u) {
    return __uint_as_float(((uint_t)u) << 16);
}
__device__ __forceinline__ ushort_t f2bf(float f) {
    const uint_t u = __float_as_uint(f);
    return (ushort_t)((u + 0x7fffu + ((u >> 16) & 1u)) >> 16);   // RNE
}

// MFMA 16x16x32 bf16 via inline asm. D=C tied ("+v").
//   A[m][k]: m = lane&15, k = (lane>>4)*8 + j
//   B[k][n]: n = lane&15, k = (lane>>4)*8 + j
//   D[m][n]: n = lane&15, m = (lane>>4)*4 + r
// NOTE (round 11): porting this to the decoder GEMM produced absmax 1.99
// (structural). Decoder stays fp32-VALU; MFMA only in gin kernels (proven).
__device__ __forceinline__ void mfma_acc(f32x4& acc, short8 a, short8 b) {
    asm volatile("v_mfma_f32_16x16x32_bf16 %0, %1, %2, %0"
                 : "+v"(acc) : "v"(a), "v"(b));
}
__device__ __forceinline__ void mfma_hazard_wait() {
    asm volatile("s_nop 7\n\ts_nop 7");
}

// ===========================================================================
// CSR build (by dst). 4 edges/thread: atomicAdd-with-return is ~62ns/op on a
// single dependent chain; 4 independent round-trips in flight (round 9).
// ===========================================================================
__global__ void degree_kernel(const int* __restrict__ dst, int* __restrict__ deg) {
    const int i0 = (blockIdx.x * blockDim.x + threadIdx.x) * 4;
    if (i0 + 4 <= N_EDGES) {
        const int4 d = *(const int4*)&dst[i0];
        atomicAdd(&deg[d.x], 1);
        atomicAdd(&deg[d.y], 1);
        atomicAdd(&deg[d.z], 1);
        atomicAdd(&deg[d.w], 1);
    }
}

__global__ void blockscan_kernel(const int* __restrict__ deg,
                                 int* __restrict__ row_start,
                                 int* __restrict__ blocksum) {
    __shared__ int s_wave[16];
    const int tid  = threadIdx.x;
    const int lane = tid & 63;
    const int wid  = tid >> 6;
    const int idx  = blockIdx.x * 1024 + tid;

    const int v = (idx < N_NODES) ? deg[idx] : 0;
    int x = v;
    #pragma unroll
    for (int o = 1; o < 64; o <<= 1) {
        const int y = __shfl_up(x, o);
        if (lane >= o) x += y;
    }
    if (lane == 63) s_wave[wid] = x;
    __syncthreads();
    if (tid == 0) {
        int run = 0;
        #pragma unroll
        for (int w = 0; w < 16; ++w) { const int t = s_wave[w]; s_wave[w] = run; run += t; }
        blocksum[blockIdx.x] = run;
    }
    __syncthreads();
    if (idx < N_NODES) row_start[idx] = s_wave[wid] + x - v;
}

// Stage 2: add prefix of blocksums; write cursor; zero `summed` (fused here:
// this kernel runs before gin2, which now atomically accumulates into summed).
__global__ void scan_fixup_kernel(int* __restrict__ row_start,
                                  int* __restrict__ cursor,
                                  const int* __restrict__ blocksum,
                                  float* __restrict__ summed) {
    __shared__ int s_off;
    const int bid = blockIdx.x;
    const int tid = threadIdx.x;
    if (tid < 64) {
        int v = (tid < bid) ? blocksum[tid] : 0;
        #pragma unroll
        for (int o = 32; o > 0; o >>= 1) v += __shfl_down(v, o);
        if (tid == 0) s_off = v;
    }
    __syncthreads();
    const int idx = bid * 1024 + tid;
    if (idx < N_NODES) {
        const int r = row_start[idx] + s_off;
        row_start[idx] = r;
        cursor[idx] = r;
    }
    if (idx < NUM_GRAPHS * HIDDEN) summed[idx] = 0.f;
    if (bid == 0 && tid == 0) row_start[N_NODES] = N_EDGES;
}

__global__ void csr_fill_kernel(const int* __restrict__ src,
                                const int* __restrict__ dst,
                                int* __restrict__ cursor,
                                int* __restrict__ nbr) {
    const int i0 = (blockIdx.x * blockDim.x + threadIdx.x) * 4;
    if (i0 + 4 <= N_EDGES) {
        const int4 d = *(const int4*)&dst[i0];
        const int4 s = *(const int4*)&src[i0];
        const int p0 = atomicAdd(&cursor[d.x], 1);
        const int p1 = atomicAdd(&cursor[d.y], 1);
        const int p2 = atomicAdd(&cursor[d.z], 1);
        const int p3 = atomicAdd(&cursor[d.w], 1);
        nbr[p0] = s.x; nbr[p1] = s.y; nbr[p2] = s.z; nbr[p3] = s.w;
    }
}

// ===========================================================================
// Weight pack x3 (GIN): 128x128 fp32 -> bf16 MFMA B-fragments.
// ===========================================================================
__global__ void pack_w3_kernel(const float* __restrict__ wA, ushort_t* __restrict__ oA,
                               const float* __restrict__ wB, ushort_t* __restrict__ oB,
                               const float* __restrict__ wC, ushort_t* __restrict__ oC) {
    const int gid = blockIdx.x * blockDim.x + threadIdx.x;   // 49152
    const int sel = gid >> 14;
    const int idx = gid & 16383;
    const float* w = (sel == 0) ? wA : (sel == 1) ? wB : wC;
    ushort_t* out  = (sel == 0) ? oA : (sel == 1) ? oB : oC;
    const int j    = idx & 7;
    const int lane = (idx >> 3) & 63;
    const int kb   = (idx >> 9) & 3;
    const int nt   = idx >> 11;
    const int k = kb * 32 + ((lane >> 4) << 3) + j;
    const int n = (nt << 4) + (lane & 15);
    out[idx] = f2bf(w[k * HIDDEN + n]);
}

// ===========================================================================
// Fused GIN layer 1: gather(x,16) + VALU MLP-A(16->128) + MFMA MLP-B.
// ===========================================================================
__global__ void gin1_fused_kernel(const float* __restrict__ in,
                                  const int* __restrict__ row_start,
                                  const int* __restrict__ nbr,
                                  const float* __restrict__ wa, const float* __restrict__ ba,
                                  const ushort_t* __restrict__ wpkb, const float* __restrict__ bb,
                                  ushort_t* __restrict__ out) {
    __shared__ float s_in[16][NODE_DIM + 1];                 // stride 17
    __shared__ __align__(16) ushort_t s_mid[16][HIDDEN + 8]; // bf16, stride 136
    const int tid = threadIdx.x;
    const int n0  = blockIdx.x * 16;

    {   // gather: 8 groups x 16 dims, 2 nodes/group, 4-acc ILP
        const int grp = tid >> 4;
        const int k   = tid & 15;
        #pragma unroll
        for (int half = 0; half < 2; ++half) {
            const int i = grp + half * 8;
            const int n = n0 + i;
            const int beg = row_start[n], end = row_start[n + 1];
            float a0 = in[(long)n * NODE_DIM + k], a1 = 0.f, a2 = 0.f, a3 = 0.f;
            int p = beg;
            for (; p + 4 <= end; p += 4) {
                const int e0 = nbr[p], e1 = nbr[p + 1], e2 = nbr[p + 2], e3 = nbr[p + 3];
                a0 += in[(long)e0 * NODE_DIM + k];
                a1 += in[(long)e1 * NODE_DIM + k];
                a2 += in[(long)e2 * NODE_DIM + k];
                a3 += in[(long)e3 * NODE_DIM + k];
            }
            for (; p < end; ++p) a0 += in[(long)nbr[p] * NODE_DIM + k];
            s_in[i][k] = (a0 + a1) + (a2 + a3);
        }
    }
    __syncthreads();

    {   // layer A (K=16), VALU 4x4 tile, write s_mid bf16
        const int dq = tid & 31;  const int d0 = dq * 4;
        const int iq = tid >> 5;  const int i0 = iq * 4;
        float acc[4][4];
        const float4 bv = *(const float4*)&ba[d0];
        #pragma unroll
        for (int j = 0; j < 4; ++j) {
            acc[j][0] = bv.x; acc[j][1] = bv.y; acc[j][2] = bv.z; acc[j][3] = bv.w;
        }
        for (int k = 0; k < NODE_DIM; ++k) {
            const float4 w = *(const float4*)&wa[k * HIDDEN + d0];
            #pragma unroll
            for (int j = 0; j < 4; ++j) {
                const float a = s_in[i0 + j][k];
                acc[j][0] += a * w.x; acc[j][1] += a * w.y;
                acc[j][2] += a * w.z; acc[j][3] += a * w.w;
            }
        }
        #pragma unroll
        for (int j = 0; j < 4; ++j) {
            ushort4 v;
            v.x = f2bf(fmaxf(acc[j][0], 0.f)); v.y = f2bf(fmaxf(acc[j][1], 0.f));
            v.z = f2bf(fmaxf(acc[j][2], 0.f)); v.w = f2bf(fmaxf(acc[j][3], 0.f));
            *(ushort4*)&s_mid[i0 + j][d0] = v;
        }
    }
    __syncthreads();

    {   // layer B (K=128) on MFMA -> h1 bf16
        const int lane = tid & 63;
        const int wv   = tid >> 6;
        short8 afr[4];
        #pragma unroll
        for (int kb = 0; kb < 4; ++kb)
            afr[kb] = *(const short8*)&s_mid[lane & 15][kb * 32 + ((lane >> 4) << 3)];
        const int col = lane & 15;
        const int r0  = (lane >> 4) << 2;
        #pragma unroll
        for (int t = 0; t < 4; ++t) {
            const int nt = wv * 4 + t;
            short8 bfr[4];
            #pragma unroll
            for (int kb = 0; kb < 4; ++kb)
                bfr[kb] = *(const short8*)&wpkb[(((nt << 2) | kb) << 9) + (lane << 3)];
            f32x4 acc = {0.f, 0.f, 0.f, 0.f};
            #pragma unroll
            for (int kb = 0; kb < 4; ++kb) mfma_acc(acc, afr[kb], bfr[kb]);
            mfma_hazard_wait();
            const float bias = bb[nt * 16 + col];
            #pragma unroll
            for (int r = 0; r < 4; ++r)
                out[(long)(n0 + r0 + r) * HIDDEN + nt * 16 + col] =
                    f2bf(fmaxf(acc[r] + bias, 0.f));
        }
    }
}

// ===========================================================================
// Fused GIN layer 2 + POOL (round 14): gather(h1 bf16) + MFMA MLP A/B, then
// layer-B output stays in LDS and is run-length pooled into `summed` directly
// (batch sorted -> ~1.2 atomics/thread). h2 never touches global memory:
// saves 25.6MB write + 25.6MB read + the pool kernel + a memset launch.
// ===========================================================================
__global__ void gin2_fused_kernel(const ushort_t* __restrict__ in,
                                  const int* __restrict__ row_start,
                                  const int* __restrict__ nbr,
                                  const int* __restrict__ batch,
                                  const ushort_t* __restrict__ wpka, const float* __restrict__ ba,
                                  const ushort_t* __restrict__ wpkb, const float* __restrict__ bb,
                                  float* __restrict__ summed) {
    __shared__ __align__(16) ushort_t s_in[16][HIDDEN + 8];   // bf16, stride 136
    __shared__ __align__(16) ushort_t s_mid[16][HIDDEN + 8];  // bf16, stride 136
    __shared__ float s_h2[16][HIDDEN + 1];                    // fp32, stride 129
    __shared__ int s_b[16];
    const int tid  = threadIdx.x;
    const int lane = tid & 63;
    const int wv   = tid >> 6;                 // 0..1
    const int n0   = blockIdx.x * 16;

    if (tid < 16) s_b[tid] = batch[n0 + tid];

    {   // gather: wave wv -> nodes wv*8..wv*8+7, lane = bf16 pair, 8-acc ILP
        const int d2 = lane * 2;
        #pragma unroll
        for (int t = 0; t < 8; ++t) {
            const int i = wv * 8 + t;
            const int n = n0 + i;
            const int beg = row_start[n], end = row_start[n + 1];
            const uint_t sv = *(const uint_t*)&in[(long)n * HIDDEN + d2];
            float ax[8], ay[8];
            ax[0] = bf2f(sv & 0xffffu); ay[0] = bf2f(sv >> 16);
            #pragma unroll
            for (int q = 1; q < 8; ++q) { ax[q] = 0.f; ay[q] = 0.f; }
            int p = beg;
            for (; p + 8 <= end; p += 8) {
                uint_t v[8];
                #pragma unroll
                for (int q = 0; q < 8; ++q)
                    v[q] = *(const uint_t*)&in[(long)nbr[p + q] * HIDDEN + d2];
                #pragma unroll
                for (int q = 0; q < 8; ++q) {
                    ax[q] += bf2f(v[q] & 0xffffu); ay[q] += bf2f(v[q] >> 16);
                }
            }
            for (; p + 2 <= end; p += 2) {
                const uint_t v0 = *(const uint_t*)&in[(long)nbr[p]     * HIDDEN + d2];
                const uint_t v1 = *(const uint_t*)&in[(long)nbr[p + 1] * HIDDEN + d2];
                ax[0] += bf2f(v0 & 0xffffu); ay[0] += bf2f(v0 >> 16);
                ax[1] += bf2f(v1 & 0xffffu); ay[1] += bf2f(v1 >> 16);
            }
            if (p < end) {
                const uint_t v0 = *(const uint_t*)&in[(long)nbr[p] * HIDDEN + d2];
                ax[0] += bf2f(v0 & 0xffffu); ay[0] += bf2f(v0 >> 16);
            }
            const float rx = ((ax[0] + ax[1]) + (ax[2] + ax[3])) + ((ax[4] + ax[5]) + (ax[6] + ax[7]));
            const float ry = ((ay[0] + ay[1]) + (ay[2] + ay[3])) + ((ay[4] + ay[5]) + (ay[6] + ay[7]));
            const uint_t packed = (uint_t)f2bf(rx) | ((uint_t)f2bf(ry) << 16);
            *(uint_t*)&s_in[i][d2] = packed;
        }
    }
    __syncthreads();

    const int col = lane & 15;
    const int r0  = (lane >> 4) << 2;

    {   // layer A (K=128) on MFMA -> s_mid bf16
        short8 afr[4];
        #pragma unroll
        for (int kb = 0; kb < 4; ++kb)
            afr[kb] = *(const short8*)&s_in[lane & 15][kb * 32 + ((lane >> 4) << 3)];
        #pragma unroll
        for (int t = 0; t < 4; ++t) {
            const int nt = wv * 4 + t;
            short8 bfr[4];
            #pragma unroll
            for (int kb = 0; kb < 4; ++kb)
                bfr[kb] = *(const short8*)&wpka[(((nt << 2) | kb) << 9) + (lane << 3)];
            f32x4 acc = {0.f, 0.f, 0.f, 0.f};
            #pragma unroll
            for (int kb = 0; kb < 4; ++kb) mfma_acc(acc, afr[kb], bfr[kb]);
            mfma_hazard_wait();
            const float bias = ba[nt * 16 + col];
            #pragma unroll
            for (int r = 0; r < 4; ++r)
                s_mid[r0 + r][nt * 16 + col] = f2bf(fmaxf(acc[r] + bias, 0.f));
        }
    }
    __syncthreads();

    {   // layer B (K=128) on MFMA -> s_h2 (LDS only)
        short8 afr[4];
        #pragma unroll
        for (int kb = 0; kb < 4; ++kb)
            afr[kb] = *(const short8*)&s_mid[lane & 15][kb * 32 + ((lane >> 4) << 3)];
        #pragma unroll
        for (int t = 0; t < 4; ++t) {
            const int nt = wv * 4 + t;
            short8 bfr[4];
            #pragma unroll
            for (int kb = 0; kb < 4; ++kb)
                bfr[kb] = *(const short8*)&wpkb[(((nt << 2) | kb) << 9) + (lane << 3)];
            f32x4 acc = {0.f, 0.f, 0.f, 0.f};
            #pragma unroll
            for (int kb = 0; kb < 4; ++kb) mfma_acc(acc, afr[kb], bfr[kb]);
            mfma_hazard_wait();
            const float bias = bb[nt * 16 + col];
            #pragma unroll
            for (int r = 0; r < 4; ++r)
                s_h2[r0 + r][nt * 16 + col] = fmaxf(acc[r] + bias, 0.f);
        }
    }
    __syncthreads();

    {   // fused mean-pool partial: run-length over the 16 sorted nodes
        const int d = tid & 127;   // one owner per dim (128 threads)
        int cur = s_b[0];
        float acc = 0.f;
        #pragma unroll
        for (int i = 0; i < 16; ++i) {
            const int g = s_b[i];
            if (g != cur) {
                atomicAdd(&summed[cur * HIDDEN + d], acc);
                acc = 0.f; cur = g;
            }
            acc += s_h2[i][d];
        }
        atomicAdd(&summed[cur * HIDDEN + d], acc);
    }
}

// ---------------------------------------------------------------------------
// Per-graph head: pooled -> mu, logvar, z -> hd. Counts via binary search on
// the sorted batch array (round 14: replaces the pool kernel's counts).
// ---------------------------------------------------------------------------
__global__ void head_kernel(const float* __restrict__ summed,
                            const int* __restrict__ batch,
                            const float* __restrict__ eps,
                            const float* __restrict__ wmu, const float* __restrict__ bmu,
                            const float* __restrict__ wlv, const float* __restrict__ blv,
                            const float* __restrict__ wd1, const float* __restrict__ bd1,
                            const float* __restrict__ wd2, const float* __restrict__ bd2,
                            float* __restrict__ out_mu, float* __restrict__ out_lv,
                            float* __restrict__ hd) {
    const int g = blockIdx.x;
    const int d = threadIdx.x;
    __shared__ float s_pool[HIDDEN];
    __shared__ float s_z[LATENT];
    __shared__ float s_h1[HIDDEN];
    __shared__ float s_cnt;

    if (d == 0) {
        int lo = 0, hi = N_NODES;
        while (lo < hi) { const int m = (lo + hi) >> 1; if (batch[m] < g) lo = m + 1; else hi = m; }
        int lo2 = lo, hi2 = N_NODES;
        while (lo2 < hi2) { const int m = (lo2 + hi2) >> 1; if (batch[m] < g + 1) lo2 = m + 1; else hi2 = m; }
        s_cnt = fmaxf((float)(lo2 - lo), 1.f);
    }
    __syncthreads();
    s_pool[d] = summed[g * HIDDEN + d] / s_cnt;
    __syncthreads();

    if (d < LATENT) {
        float m = bmu[d], lv = blv[d];
        for (int k = 0; k < HIDDEN; ++k) {
            const float p = s_pool[k];
            m  += p * wmu[k * LATENT + d];
            lv += p * wlv[k * LATENT + d];
        }
        lv = fminf(fmaxf(lv, -5.f), 5.f);
        out_mu[g * LATENT + d] = m;
        out_lv[g * LATENT + d] = lv;
        s_z[d] = m + eps[g * LATENT + d] * expf(0.5f * lv);
    }
    __syncthreads();
    {
        float a = bd1[d];
        for (int k = 0; k < LATENT; ++k) a += s_z[k] * wd1[k * HIDDEN + d];
        s_h1[d] = fmaxf(a, 0.f);
    }
    __syncthreads();
    {
        float a = bd2[d];
        for (int k = 0; k < HIDDEN; ++k) a += s_h1[k] * wd2[k * HIDDEN + d];
        hd[g * HIDDEN + d] = a;
    }
}

// ---------------------------------------------------------------------------
// Decoder GEMM (merged adj+nf), fp32. GB=16 (752 blocks) + float4 W loads +
// 4-col threads + manual 8-deep W prefetch (round 13: 8 independent loads in
// flight; the k-loop is L2-latency-bound).
// ---------------------------------------------------------------------------
#define GB2 16
#define ADJ_BLOCKS 40   // ceil(10000/256)
__global__ void decoder_gemm2_kernel(const float* __restrict__ hd,
                                     const float* __restrict__ we, const float* __restrict__ be,
                                     float* __restrict__ raw_adj,
                                     const float* __restrict__ wn, const float* __restrict__ bn,
                                     float* __restrict__ raw_nf) {
    const int g0 = blockIdx.y * GB2;
    const bool is_adj = (blockIdx.x < ADJ_BLOCKS);
    const float* W    = is_adj ? we : wn;
    const float* bias = is_adj ? be : bn;
    float* raw        = is_adj ? raw_adj : raw_nf;
    const int N       = is_adj ? (MAX_NODES * MAX_NODES) : (MAX_NODES * NODE_DIM);
    const int bx      = is_adj ? blockIdx.x : blockIdx.x - ADJ_BLOCKS;
    const int cg = threadIdx.x & 63;    // column group: 4 cols
    const int gg = threadIdx.x >> 6;    // graph group: 4 graphs
    const int o0 = bx * 256 + cg * 4;

    __shared__ float s_hd[GB2][HIDDEN]; // 8KB
    for (int idx = threadIdx.x; idx < GB2 * HIDDEN; idx += 256) {
        s_hd[idx >> 7][idx & 127] = hd[(long)(g0 + (idx >> 7)) * HIDDEN + (idx & 127)];
    }
    __syncthreads();
    if (o0 >= N) return;   // safe: no barriers after this point

    float4 acc[4];
    const float4 bv = *(const float4*)&bias[o0];
    #pragma unroll
    for (int j = 0; j < 4; ++j) acc[j] = bv;

    for (int k0 = 0; k0 < HIDDEN; k0 += 8) {
        float4 w[8];
        #pragma unroll
        for (int u = 0; u < 8; ++u)
            w[u] = *(const float4*)&W[(long)(k0 + u) * N + o0];
        #pragma unroll
        for (int u = 0; u < 8; ++u) {
            #pragma unroll
            for (int j = 0; j < 4; ++j) {
                const float a = s_hd[gg * 4 + j][k0 + u];   // wave-uniform broadcast
                acc[j].x += a * w[u].x; acc[j].y += a * w[u].y;
                acc[j].z += a * w[u].z; acc[j].w += a * w[u].w;
            }
        }
    }
    #pragma unroll
    for (int j = 0; j < 4; ++j)
        *(float4*)&raw[(long)(g0 + gg * 4 + j) * N + o0] = acc[j];
}

// ---------------------------------------------------------------------------
// Merged epilogue: blocks [0,256) = adj symmetrize/clip; [256,306) = softmax.
// ---------------------------------------------------------------------------
__global__ void epilogue_kernel(const float* __restrict__ raw_adj,
                                float* __restrict__ out_adj,
                                const float* __restrict__ raw_nf,
                                float* __restrict__ out_nf) {
    const int tid = threadIdx.x;
    if (blockIdx.x < NUM_GRAPHS) {
        const int g = blockIdx.x;
        __shared__ float s_a[MAX_NODES * MAX_NODES];
        const float* r = raw_adj + (long)g * MAX_NODES * MAX_NODES;
        for (int o = tid; o < MAX_NODES * MAX_NODES; o += blockDim.x) s_a[o] = r[o];
        __syncthreads();
        float* w = out_adj + (long)g * MAX_NODES * MAX_NODES;
        for (int o = tid; o < MAX_NODES * MAX_NODES; o += blockDim.x) {
            const int i = o / MAX_NODES;
            const int j = o - i * MAX_NODES;
            float v;
            if (i == j) v = -10.f;
            else        v = fminf(fmaxf(0.5f * (s_a[o] + s_a[j * MAX_NODES + i]), -10.f), 10.f);
            w[o] = v;
        }
    } else {
        const int idx = (blockIdx.x - NUM_GRAPHS) * blockDim.x + tid;  // (g,m)
        if (idx >= NUM_GRAPHS * MAX_NODES) return;
        const float* r = raw_nf + (long)idx * NODE_DIM;
        float mx = -1e30f;
        #pragma unroll
        for (int d = 0; d < NODE_DIM; ++d) mx = fmaxf(mx, r[d]);
        float e[NODE_DIM];
        float s = 0.f;
        #pragma unroll
        for (int d = 0; d < NODE_DIM; ++d) { e[d] = expf(r[d] - mx); s += e[d]; }
        const float inv = 1.f / s;
        float* w = out_nf + (long)idx * NODE_DIM;
        #pragma unroll
        for (int d = 0; d < NODE_DIM; ++d) w[d] = e[d] * inv;
    }
}

// ---------------------------------------------------------------------------
extern "C" void kernel_launch(void* const* d_in, const int* in_sizes, int n_in,
                              void* d_out, int out_size, void* d_ws, size_t ws_size,
                              hipStream_t stream) {
    const float* x    = (const float*)d_in[0];
    const int*   edge = (const int*)d_in[1];
    const int*   src  = edge;
    const int*   dst  = edge + N_EDGES;
    const int*   batch = (const int*)d_in[2];
    const float* eps  = (const float*)d_in[3];
    const float* w1a = (const float*)d_in[4],  *b1a = (const float*)d_in[5];
    const float* w1b = (const float*)d_in[6],  *b1b = (const float*)d_in[7];
    const float* w2a = (const float*)d_in[8],  *b2a = (const float*)d_in[9];
    const float* w2b = (const float*)d_in[10], *b2b = (const float*)d_in[11];
    const float* wmu = (const float*)d_in[12], *bmu = (const float*)d_in[13];
    const float* wlv = (const float*)d_in[14], *blv = (const float*)d_in[15];
    const float* wd1 = (const float*)d_in[16], *bd1 = (const float*)d_in[17];
    const float* wd2 = (const float*)d_in[18], *bd2 = (const float*)d_in[19];
    const float* wn  = (const float*)d_in[20], *bn  = (const float*)d_in[21];
    const float* we  = (const float*)d_in[22], *be  = (const float*)d_in[23];

    float* out = (float*)d_out;
    float* out_adj = out;                                                  // 2,560,000
    float* out_nf  = out + (long)NUM_GRAPHS * MAX_NODES * MAX_NODES;       // 409,600
    float* out_mu  = out_nf + (long)NUM_GRAPHS * MAX_NODES * NODE_DIM;     // 16,384
    float* out_lv  = out_mu + NUM_GRAPHS * LATENT;                         // 16,384

    float* ws = (float*)d_ws;
    ushort_t* h1 = (ushort_t*)ws;                     // 6.4M bf16 = 3.2M floats
    float* summed = ws + 3200000;                     // 32,768
    float* hd     = summed + NUM_GRAPHS * HIDDEN;     // 32,768
    int*   deg       = (int*)(hd + NUM_GRAPHS * HIDDEN);
    int*   row_start = deg + N_NODES;                 // 50,001 ints
    int*   cursor    = row_start + N_NODES + 1;       // 50,000 ints
    int*   nbr       = cursor + N_NODES;              // 640,000 ints
    int*   blocksum  = nbr + N_EDGES;                 // 49 ints
    ushort_t* wpk1b = (ushort_t*)(((uintptr_t)(blocksum + 64) + 15) & ~(uintptr_t)15);
    ushort_t* wpk2a = wpk1b + HIDDEN * HIDDEN;        // 16,384 each
    ushort_t* wpk2b = wpk2a + HIDDEN * HIDDEN;
    // raw decoder buffers reuse the h1 region (dead after gin2): 2.97M < 3.2M
    float* raw_adj = (float*)h1;
    float* raw_nf  = (float*)h1 + (long)NUM_GRAPHS * MAX_NODES * MAX_NODES;

    // ---- CSR build + weight pack ----
    hipMemsetAsync(deg, 0, sizeof(int) * N_NODES, stream);
    degree_kernel<<<N_EDGES / 4 / 256, 256, 0, stream>>>(dst, deg);
    blockscan_kernel<<<(N_NODES + 1023) / 1024, 1024, 0, stream>>>(deg, row_start, blocksum);
    scan_fixup_kernel<<<(N_NODES + 1023) / 1024, 1024, 0, stream>>>(row_start, cursor,
                                                                    blocksum, summed);
    csr_fill_kernel<<<N_EDGES / 4 / 256, 256, 0, stream>>>(src, dst, cursor, nbr);
    pack_w3_kernel<<<192, 256, 0, stream>>>(w1b, wpk1b, w2a, wpk2a, w2b, wpk2b);

    // ---- GIN layers (gin2 fuses the mean-pool partials) ----
    gin1_fused_kernel<<<N_NODES / 16, 128, 0, stream>>>(x, row_start, nbr,
                                                        w1a, b1a, wpk1b, b1b, h1);
    gin2_fused_kernel<<<N_NODES / 16, 128, 0, stream>>>(h1, row_start, nbr, batch,
                                                        wpk2a, b2a, wpk2b, b2b, summed);

    // ---- heads + reparam + decoder trunk (counts via binary search) ----
    head_kernel<<<NUM_GRAPHS, 128, 0, stream>>>(summed, batch, eps,
                                                wmu, bmu, wlv, blv,
                                                wd1, bd1, wd2, bd2,
                                                out_mu, out_lv, hd);

    // ---- decoder GEMMs (merged, GB=16, 8-deep prefetch) ----
    {
        dim3 grid(ADJ_BLOCKS + 7, NUM_GRAPHS / GB2);   // 47 x 16 = 752 blocks
        decoder_gemm2_kernel<<<grid, 256, 0, stream>>>(hd, we, be, raw_adj,
                                                       wn, bn, raw_nf);
    }

    // ---- merged epilogue: adj sym/clip + nf softmax ----
    epilogue_kernel<<<NUM_GRAPHS + 50, 512, 0, stream>>>(raw_adj, out_adj,
                                                         raw_nf, out_nf);
}

// Round 15
// 186.417 us; speedup vs baseline: 1.0995x; 1.0995x over previous
//
#include <hip/hip_runtime.h>
#include <hip/hip_bf16.h>

#define N_NODES   50000
#define N_EDGES   640000
#define NODE_DIM  16
#define HIDDEN    128
#define LATENT    64
#define MAX_NODES 100
#define NUM_GRAPHS 256

typedef unsigned short ushort_t;
typedef unsigned int   uint_t;
typedef short  short8 __attribute__((ext_vector_type(8)));   // 8 bf16 = 4 VGPR
typedef float  f32x4  __attribute__((ext_vector_type(4)));

__device__ __forceinline__ float bf2f(ushort_t u) {
    return __uint_as_float(((uint_t)u) << 16);
}
__device__ __forceinline__ ushort_t f2bf(float f) {
    const uint_t u = __float_as_uint(f);
    return (ushort_t)((u + 0x7fffu + ((u >> 16) & 1u)) >> 16);   // RNE
}

// MFMA 16x16x32 bf16 via inline asm. D=C tied ("+v").
//   A[m][k]: m = lane&15, k = (lane>>4)*8 + j
//   B[k][n]: n = lane&15, k = (lane>>4)*8 + j
//   D[m][n]: n = lane&15, m = (lane>>4)*4 + r
// NOTE (round 11): porting this to the decoder GEMM produced absmax 1.99
// (structural). Decoder stays fp32-VALU; MFMA only in gin kernels (proven).
__device__ __forceinline__ void mfma_acc(f32x4& acc, short8 a, short8 b) {
    asm volatile("v_mfma_f32_16x16x32_bf16 %0, %1, %2, %0"
                 : "+v"(acc) : "v"(a), "v"(b));
}
__device__ __forceinline__ void mfma_hazard_wait() {
    asm volatile("s_nop 7\n\ts_nop 7");
}

// ===========================================================================
// CSR build (by dst). 4 edges/thread: atomicAdd-with-return is ~62ns/op on a
// single dependent chain; 4 independent round-trips in flight (round 9).
// ===========================================================================
__global__ void degree_kernel(const int* __restrict__ dst, int* __restrict__ deg) {
    const int i0 = (blockIdx.x * blockDim.x + threadIdx.x) * 4;
    if (i0 + 4 <= N_EDGES) {
        const int4 d = *(const int4*)&dst[i0];
        atomicAdd(&deg[d.x], 1);
        atomicAdd(&deg[d.y], 1);
        atomicAdd(&deg[d.z], 1);
        atomicAdd(&deg[d.w], 1);
    }
}

__global__ void blockscan_kernel(const int* __restrict__ deg,
                                 int* __restrict__ row_start,
                                 int* __restrict__ blocksum) {
    __shared__ int s_wave[16];
    const int tid  = threadIdx.x;
    const int lane = tid & 63;
    const int wid  = tid >> 6;
    const int idx  = blockIdx.x * 1024 + tid;

    const int v = (idx < N_NODES) ? deg[idx] : 0;
    int x = v;
    #pragma unroll
    for (int o = 1; o < 64; o <<= 1) {
        const int y = __shfl_up(x, o);
        if (lane >= o) x += y;
    }
    if (lane == 63) s_wave[wid] = x;
    __syncthreads();
    if (tid == 0) {
        int run = 0;
        #pragma unroll
        for (int w = 0; w < 16; ++w) { const int t = s_wave[w]; s_wave[w] = run; run += t; }
        blocksum[blockIdx.x] = run;
    }
    __syncthreads();
    if (idx < N_NODES) row_start[idx] = s_wave[wid] + x - v;
}

// Stage 2: add prefix of blocksums; write cursor; zero `summed` (fused:
// runs before gin2, which accumulates pool partials into summed).
__global__ void scan_fixup_kernel(int* __restrict__ row_start,
                                  int* __restrict__ cursor,
                                  const int* __restrict__ blocksum,
                                  float* __restrict__ summed) {
    __shared__ int s_off;
    const int bid = blockIdx.x;
    const int tid = threadIdx.x;
    if (tid < 64) {
        int v = (tid < bid) ? blocksum[tid] : 0;
        #pragma unroll
        for (int o = 32; o > 0; o >>= 1) v += __shfl_down(v, o);
        if (tid == 0) s_off = v;
    }
    __syncthreads();
    const int idx = bid * 1024 + tid;
    if (idx < N_NODES) {
        const int r = row_start[idx] + s_off;
        row_start[idx] = r;
        cursor[idx] = r;
    }
    if (idx < NUM_GRAPHS * HIDDEN) summed[idx] = 0.f;
    if (bid == 0 && tid == 0) row_start[N_NODES] = N_EDGES;
}

__global__ void csr_fill_kernel(const int* __restrict__ src,
                                const int* __restrict__ dst,
                                int* __restrict__ cursor,
                                int* __restrict__ nbr) {
    const int i0 = (blockIdx.x * blockDim.x + threadIdx.x) * 4;
    if (i0 + 4 <= N_EDGES) {
        const int4 d = *(const int4*)&dst[i0];
        const int4 s = *(const int4*)&src[i0];
        const int p0 = atomicAdd(&cursor[d.x], 1);
        const int p1 = atomicAdd(&cursor[d.y], 1);
        const int p2 = atomicAdd(&cursor[d.z], 1);
        const int p3 = atomicAdd(&cursor[d.w], 1);
        nbr[p0] = s.x; nbr[p1] = s.y; nbr[p2] = s.z; nbr[p3] = s.w;
    }
}

// ===========================================================================
// Weight pack x3 (GIN): 128x128 fp32 -> bf16 MFMA B-fragments.
// ===========================================================================
__global__ void pack_w3_kernel(const float* __restrict__ wA, ushort_t* __restrict__ oA,
                               const float* __restrict__ wB, ushort_t* __restrict__ oB,
                               const float* __restrict__ wC, ushort_t* __restrict__ oC) {
    const int gid = blockIdx.x * blockDim.x + threadIdx.x;   // 49152
    const int sel = gid >> 14;
    const int idx = gid & 16383;
    const float* w = (sel == 0) ? wA : (sel == 1) ? wB : wC;
    ushort_t* out  = (sel == 0) ? oA : (sel == 1) ? oB : oC;
    const int j    = idx & 7;
    const int lane = (idx >> 3) & 63;
    const int kb   = (idx >> 9) & 3;
    const int nt   = idx >> 11;
    const int k = kb * 32 + ((lane >> 4) << 3) + j;
    const int n = (nt << 4) + (lane & 15);
    out[idx] = f2bf(w[k * HIDDEN + n]);
}

// ===========================================================================
// Fused GIN layer 1: gather(x,16) + VALU MLP-A(16->128) + MFMA MLP-B.
// ===========================================================================
__global__ void gin1_fused_kernel(const float* __restrict__ in,
                                  const int* __restrict__ row_start,
                                  const int* __restrict__ nbr,
                                  const float* __restrict__ wa, const float* __restrict__ ba,
                                  const ushort_t* __restrict__ wpkb, const float* __restrict__ bb,
                                  ushort_t* __restrict__ out) {
    __shared__ float s_in[16][NODE_DIM + 1];                 // stride 17
    __shared__ __align__(16) ushort_t s_mid[16][HIDDEN + 8]; // bf16, stride 136
    const int tid = threadIdx.x;
    const int n0  = blockIdx.x * 16;

    {   // gather: 8 groups x 16 dims, 2 nodes/group, 4-acc ILP
        const int grp = tid >> 4;
        const int k   = tid & 15;
        #pragma unroll
        for (int half = 0; half < 2; ++half) {
            const int i = grp + half * 8;
            const int n = n0 + i;
            const int beg = row_start[n], end = row_start[n + 1];
            float a0 = in[(long)n * NODE_DIM + k], a1 = 0.f, a2 = 0.f, a3 = 0.f;
            int p = beg;
            for (; p + 4 <= end; p += 4) {
                const int e0 = nbr[p], e1 = nbr[p + 1], e2 = nbr[p + 2], e3 = nbr[p + 3];
                a0 += in[(long)e0 * NODE_DIM + k];
                a1 += in[(long)e1 * NODE_DIM + k];
                a2 += in[(long)e2 * NODE_DIM + k];
                a3 += in[(long)e3 * NODE_DIM + k];
            }
            for (; p < end; ++p) a0 += in[(long)nbr[p] * NODE_DIM + k];
            s_in[i][k] = (a0 + a1) + (a2 + a3);
        }
    }
    __syncthreads();

    {   // layer A (K=16), VALU 4x4 tile, write s_mid bf16
        const int dq = tid & 31;  const int d0 = dq * 4;
        const int iq = tid >> 5;  const int i0 = iq * 4;
        float acc[4][4];
        const float4 bv = *(const float4*)&ba[d0];
        #pragma unroll
        for (int j = 0; j < 4; ++j) {
            acc[j][0] = bv.x; acc[j][1] = bv.y; acc[j][2] = bv.z; acc[j][3] = bv.w;
        }
        for (int k = 0; k < NODE_DIM; ++k) {
            const float4 w = *(const float4*)&wa[k * HIDDEN + d0];
            #pragma unroll
            for (int j = 0; j < 4; ++j) {
                const float a = s_in[i0 + j][k];
                acc[j][0] += a * w.x; acc[j][1] += a * w.y;
                acc[j][2] += a * w.z; acc[j][3] += a * w.w;
            }
        }
        #pragma unroll
        for (int j = 0; j < 4; ++j) {
            ushort4 v;
            v.x = f2bf(fmaxf(acc[j][0], 0.f)); v.y = f2bf(fmaxf(acc[j][1], 0.f));
            v.z = f2bf(fmaxf(acc[j][2], 0.f)); v.w = f2bf(fmaxf(acc[j][3], 0.f));
            *(ushort4*)&s_mid[i0 + j][d0] = v;
        }
    }
    __syncthreads();

    {   // layer B (K=128) on MFMA -> h1 bf16
        const int lane = tid & 63;
        const int wv   = tid >> 6;
        short8 afr[4];
        #pragma unroll
        for (int kb = 0; kb < 4; ++kb)
            afr[kb] = *(const short8*)&s_mid[lane & 15][kb * 32 + ((lane >> 4) << 3)];
        const int col = lane & 15;
        const int r0  = (lane >> 4) << 2;
        #pragma unroll
        for (int t = 0; t < 4; ++t) {
            const int nt = wv * 4 + t;
            short8 bfr[4];
            #pragma unroll
            for (int kb = 0; kb < 4; ++kb)
                bfr[kb] = *(const short8*)&wpkb[(((nt << 2) | kb) << 9) + (lane << 3)];
            f32x4 acc = {0.f, 0.f, 0.f, 0.f};
            #pragma unroll
            for (int kb = 0; kb < 4; ++kb) mfma_acc(acc, afr[kb], bfr[kb]);
            mfma_hazard_wait();
            const float bias = bb[nt * 16 + col];
            #pragma unroll
            for (int r = 0; r < 4; ++r)
                out[(long)(n0 + r0 + r) * HIDDEN + nt * 16 + col] =
                    f2bf(fmaxf(acc[r] + bias, 0.f));
        }
    }
}

// ===========================================================================
// Fused GIN layer 2 + POOL: gather(h1 bf16) + MFMA MLP A/B; layer-B output
// stays in LDS and is run-length pooled into `summed`. Round 15 fix: s_h2
// OVERLAYS s_in/s_mid (dead after layer-B fragments are in registers) so LDS
// stays ~12.8KB (round 14's +8.3KB dropped occupancy 43->30%), and stride is
// 132 floats (2-way bank aliasing = free per m136; round 14's 129-stride was
// 4-way overlapped -> 400K SQ_LDS_BANK_CONFLICT).
// ===========================================================================
__global__ void gin2_fused_kernel(const ushort_t* __restrict__ in,
                                  const int* __restrict__ row_start,
                                  const int* __restrict__ nbr,
                                  const int* __restrict__ batch,
                                  const ushort_t* __restrict__ wpka, const float* __restrict__ ba,
                                  const ushort_t* __restrict__ wpkb, const float* __restrict__ bb,
                                  float* __restrict__ summed) {
    // s_buf[0] = s_in, s_buf[1] = s_mid (both bf16 [16][136]); after layer-B
    // fragments are loaded both are dead -> s_h2 (float [16][132], 8448B)
    // overlays the same 8704B region.
    __shared__ __align__(16) ushort_t s_buf[2][16][HIDDEN + 8];
    __shared__ int s_b[16];
    float (*s_h2)[HIDDEN + 4] = (float(*)[HIDDEN + 4]) & s_buf[0][0][0];
    const int tid  = threadIdx.x;
    const int lane = tid & 63;
    const int wv   = tid >> 6;                 // 0..1
    const int n0   = blockIdx.x * 16;

    if (tid < 16) s_b[tid] = batch[n0 + tid];

    {   // gather: wave wv -> nodes wv*8..wv*8+7, lane = bf16 pair, 8-acc ILP
        const int d2 = lane * 2;
        #pragma unroll
        for (int t = 0; t < 8; ++t) {
            const int i = wv * 8 + t;
            const int n = n0 + i;
            const int beg = row_start[n], end = row_start[n + 1];
            const uint_t sv = *(const uint_t*)&in[(long)n * HIDDEN + d2];
            float ax[8], ay[8];
            ax[0] = bf2f(sv & 0xffffu); ay[0] = bf2f(sv >> 16);
            #pragma unroll
            for (int q = 1; q < 8; ++q) { ax[q] = 0.f; ay[q] = 0.f; }
            int p = beg;
            for (; p + 8 <= end; p += 8) {
                uint_t v[8];
                #pragma unroll
                for (int q = 0; q < 8; ++q)
                    v[q] = *(const uint_t*)&in[(long)nbr[p + q] * HIDDEN + d2];
                #pragma unroll
                for (int q = 0; q < 8; ++q) {
                    ax[q] += bf2f(v[q] & 0xffffu); ay[q] += bf2f(v[q] >> 16);
                }
            }
            for (; p + 2 <= end; p += 2) {
                const uint_t v0 = *(const uint_t*)&in[(long)nbr[p]     * HIDDEN + d2];
                const uint_t v1 = *(const uint_t*)&in[(long)nbr[p + 1] * HIDDEN + d2];
                ax[0] += bf2f(v0 & 0xffffu); ay[0] += bf2f(v0 >> 16);
                ax[1] += bf2f(v1 & 0xffffu); ay[1] += bf2f(v1 >> 16);
            }
            if (p < end) {
                const uint_t v0 = *(const uint_t*)&in[(long)nbr[p] * HIDDEN + d2];
                ax[0] += bf2f(v0 & 0xffffu); ay[0] += bf2f(v0 >> 16);
            }
            const float rx = ((ax[0] + ax[1]) + (ax[2] + ax[3])) + ((ax[4] + ax[5]) + (ax[6] + ax[7]));
            const float ry = ((ay[0] + ay[1]) + (ay[2] + ay[3])) + ((ay[4] + ay[5]) + (ay[6] + ay[7]));
            const uint_t packed = (uint_t)f2bf(rx) | ((uint_t)f2bf(ry) << 16);
            *(uint_t*)&s_buf[0][i][d2] = packed;
        }
    }
    __syncthreads();

    const int col = lane & 15;
    const int r0  = (lane >> 4) << 2;

    {   // layer A (K=128) on MFMA -> s_mid bf16
        short8 afr[4];
        #pragma unroll
        for (int kb = 0; kb < 4; ++kb)
            afr[kb] = *(const short8*)&s_buf[0][lane & 15][kb * 32 + ((lane >> 4) << 3)];
        #pragma unroll
        for (int t = 0; t < 4; ++t) {
            const int nt = wv * 4 + t;
            short8 bfr[4];
            #pragma unroll
            for (int kb = 0; kb < 4; ++kb)
                bfr[kb] = *(const short8*)&wpka[(((nt << 2) | kb) << 9) + (lane << 3)];
            f32x4 acc = {0.f, 0.f, 0.f, 0.f};
            #pragma unroll
            for (int kb = 0; kb < 4; ++kb) mfma_acc(acc, afr[kb], bfr[kb]);
            mfma_hazard_wait();
            const float bias = ba[nt * 16 + col];
            #pragma unroll
            for (int r = 0; r < 4; ++r)
                s_buf[1][r0 + r][nt * 16 + col] = f2bf(fmaxf(acc[r] + bias, 0.f));
        }
    }
    __syncthreads();

    {   // layer B (K=128) on MFMA -> s_h2 (overlays s_in/s_mid)
        short8 afr[4];
        #pragma unroll
        for (int kb = 0; kb < 4; ++kb)
            afr[kb] = *(const short8*)&s_buf[1][lane & 15][kb * 32 + ((lane >> 4) << 3)];
        __syncthreads();   // all waves hold fragments; s_in/s_mid now dead
        #pragma unroll
        for (int t = 0; t < 4; ++t) {
            const int nt = wv * 4 + t;
            short8 bfr[4];
            #pragma unroll
            for (int kb = 0; kb < 4; ++kb)
                bfr[kb] = *(const short8*)&wpkb[(((nt << 2) | kb) << 9) + (lane << 3)];
            f32x4 acc = {0.f, 0.f, 0.f, 0.f};
            #pragma unroll
            for (int kb = 0; kb < 4; ++kb) mfma_acc(acc, afr[kb], bfr[kb]);
            mfma_hazard_wait();
            const float bias = bb[nt * 16 + col];
            #pragma unroll
            for (int r = 0; r < 4; ++r)
                s_h2[r0 + r][nt * 16 + col] = fmaxf(acc[r] + bias, 0.f);
        }
    }
    __syncthreads();

    {   // fused mean-pool partial: run-length over the 16 sorted nodes
        const int d = tid & 127;   // one owner per dim (128 threads)
        int cur = s_b[0];
        float acc = 0.f;
        #pragma unroll
        for (int i = 0; i < 16; ++i) {
            const int g = s_b[i];
            if (g != cur) {
                atomicAdd(&summed[cur * HIDDEN + d], acc);
                acc = 0.f; cur = g;
            }
            acc += s_h2[i][d];
        }
        atomicAdd(&summed[cur * HIDDEN + d], acc);
    }
}

// ---------------------------------------------------------------------------
// Per-graph head: pooled -> mu, logvar, z -> hd. Counts via binary search on
// the sorted batch array.
// ---------------------------------------------------------------------------
__global__ void head_kernel(const float* __restrict__ summed,
                            const int* __restrict__ batch,
                            const float* __restrict__ eps,
                            const float* __restrict__ wmu, const float* __restrict__ bmu,
                            const float* __restrict__ wlv, const float* __restrict__ blv,
                            const float* __restrict__ wd1, const float* __restrict__ bd1,
                            const float* __restrict__ wd2, const float* __restrict__ bd2,
                            float* __restrict__ out_mu, float* __restrict__ out_lv,
                            float* __restrict__ hd) {
    const int g = blockIdx.x;
    const int d = threadIdx.x;
    __shared__ float s_pool[HIDDEN];
    __shared__ float s_z[LATENT];
    __shared__ float s_h1[HIDDEN];
    __shared__ float s_cnt;

    if (d == 0) {
        int lo = 0, hi = N_NODES;
        while (lo < hi) { const int m = (lo + hi) >> 1; if (batch[m] < g) lo = m + 1; else hi = m; }
        int lo2 = lo, hi2 = N_NODES;
        while (lo2 < hi2) { const int m = (lo2 + hi2) >> 1; if (batch[m] < g + 1) lo2 = m + 1; else hi2 = m; }
        s_cnt = fmaxf((float)(lo2 - lo), 1.f);
    }
    __syncthreads();
    s_pool[d] = summed[g * HIDDEN + d] / s_cnt;
    __syncthreads();

    if (d < LATENT) {
        float m = bmu[d], lv = blv[d];
        for (int k = 0; k < HIDDEN; ++k) {
            const float p = s_pool[k];
            m  += p * wmu[k * LATENT + d];
            lv += p * wlv[k * LATENT + d];
        }
        lv = fminf(fmaxf(lv, -5.f), 5.f);
        out_mu[g * LATENT + d] = m;
        out_lv[g * LATENT + d] = lv;
        s_z[d] = m + eps[g * LATENT + d] * expf(0.5f * lv);
    }
    __syncthreads();
    {
        float a = bd1[d];
        for (int k = 0; k < LATENT; ++k) a += s_z[k] * wd1[k * HIDDEN + d];
        s_h1[d] = fmaxf(a, 0.f);
    }
    __syncthreads();
    {
        float a = bd2[d];
        for (int k = 0; k < HIDDEN; ++k) a += s_h1[k] * wd2[k * HIDDEN + d];
        hd[g * HIDDEN + d] = a;
    }
}

// ---------------------------------------------------------------------------
// Decoder GEMM (merged adj+nf), fp32. GB=16 (752 blocks) + float4 W loads +
// 4-col threads + manual 8-deep W prefetch (round 13 proven).
// ---------------------------------------------------------------------------
#define GB2 16
#define ADJ_BLOCKS 40   // ceil(10000/256)
__global__ void decoder_gemm2_kernel(const float* __restrict__ hd,
                                     const float* __restrict__ we, const float* __restrict__ be,
                                     float* __restrict__ raw_adj,
                                     const float* __restrict__ wn, const float* __restrict__ bn,
                                     float* __restrict__ raw_nf) {
    const int g0 = blockIdx.y * GB2;
    const bool is_adj = (blockIdx.x < ADJ_BLOCKS);
    const float* W    = is_adj ? we : wn;
    const float* bias = is_adj ? be : bn;
    float* raw        = is_adj ? raw_adj : raw_nf;
    const int N       = is_adj ? (MAX_NODES * MAX_NODES) : (MAX_NODES * NODE_DIM);
    const int bx      = is_adj ? blockIdx.x : blockIdx.x - ADJ_BLOCKS;
    const int cg = threadIdx.x & 63;    // column group: 4 cols
    const int gg = threadIdx.x >> 6;    // graph group: 4 graphs
    const int o0 = bx * 256 + cg * 4;

    __shared__ float s_hd[GB2][HIDDEN]; // 8KB
    for (int idx = threadIdx.x; idx < GB2 * HIDDEN; idx += 256) {
        s_hd[idx >> 7][idx & 127] = hd[(long)(g0 + (idx >> 7)) * HIDDEN + (idx & 127)];
    }
    __syncthreads();
    if (o0 >= N) return;   // safe: no barriers after this point

    float4 acc[4];
    const float4 bv = *(const float4*)&bias[o0];
    #pragma unroll
    for (int j = 0; j < 4; ++j) acc[j] = bv;

    for (int k0 = 0; k0 < HIDDEN; k0 += 8) {
        float4 w[8];
        #pragma unroll
        for (int u = 0; u < 8; ++u)
            w[u] = *(const float4*)&W[(long)(k0 + u) * N + o0];
        #pragma unroll
        for (int u = 0; u < 8; ++u) {
            #pragma unroll
            for (int j = 0; j < 4; ++j) {
                const float a = s_hd[gg * 4 + j][k0 + u];   // wave-uniform broadcast
                acc[j].x += a * w[u].x; acc[j].y += a * w[u].y;
                acc[j].z += a * w[u].z; acc[j].w += a * w[u].w;
            }
        }
    }
    #pragma unroll
    for (int j = 0; j < 4; ++j)
        *(float4*)&raw[(long)(g0 + gg * 4 + j) * N + o0] = acc[j];
}

// ---------------------------------------------------------------------------
// Merged epilogue: blocks [0,256) = adj symmetrize/clip; [256,306) = softmax.
// ---------------------------------------------------------------------------
__global__ void epilogue_kernel(const float* __restrict__ raw_adj,
                                float* __restrict__ out_adj,
                                const float* __restrict__ raw_nf,
                                float* __restrict__ out_nf) {
    const int tid = threadIdx.x;
    if (blockIdx.x < NUM_GRAPHS) {
        const int g = blockIdx.x;
        __shared__ float s_a[MAX_NODES * MAX_NODES];
        const float* r = raw_adj + (long)g * MAX_NODES * MAX_NODES;
        for (int o = tid; o < MAX_NODES * MAX_NODES; o += blockDim.x) s_a[o] = r[o];
        __syncthreads();
        float* w = out_adj + (long)g * MAX_NODES * MAX_NODES;
        for (int o = tid; o < MAX_NODES * MAX_NODES; o += blockDim.x) {
            const int i = o / MAX_NODES;
            const int j = o - i * MAX_NODES;
            float v;
            if (i == j) v = -10.f;
            else        v = fminf(fmaxf(0.5f * (s_a[o] + s_a[j * MAX_NODES + i]), -10.f), 10.f);
            w[o] = v;
        }
    } else {
        const int idx = (blockIdx.x - NUM_GRAPHS) * blockDim.x + tid;  // (g,m)
        if (idx >= NUM_GRAPHS * MAX_NODES) return;
        const float* r = raw_nf + (long)idx * NODE_DIM;
        float mx = -1e30f;
        #pragma unroll
        for (int d = 0; d < NODE_DIM; ++d) mx = fmaxf(mx, r[d]);
        float e[NODE_DIM];
        float s = 0.f;
        #pragma unroll
        for (int d = 0; d < NODE_DIM; ++d) { e[d] = expf(r[d] - mx); s += e[d]; }
        const float inv = 1.f / s;
        float* w = out_nf + (long)idx * NODE_DIM;
        #pragma unroll
        for (int d = 0; d < NODE_DIM; ++d) w[d] = e[d] * inv;
    }
}

// ---------------------------------------------------------------------------
extern "C" void kernel_launch(void* const* d_in, const int* in_sizes, int n_in,
                              void* d_out, int out_size, void* d_ws, size_t ws_size,
                              hipStream_t stream) {
    const float* x    = (const float*)d_in[0];
    const int*   edge = (const int*)d_in[1];
    const int*   src  = edge;
    const int*   dst  = edge + N_EDGES;
    const int*   batch = (const int*)d_in[2];
    const float* eps  = (const float*)d_in[3];
    const float* w1a = (const float*)d_in[4],  *b1a = (const float*)d_in[5];
    const float* w1b = (const float*)d_in[6],  *b1b = (const float*)d_in[7];
    const float* w2a = (const float*)d_in[8],  *b2a = (const float*)d_in[9];
    const float* w2b = (const float*)d_in[10], *b2b = (const float*)d_in[11];
    const float* wmu = (const float*)d_in[12], *bmu = (const float*)d_in[13];
    const float* wlv = (const float*)d_in[14], *blv = (const float*)d_in[15];
    const float* wd1 = (const float*)d_in[16], *bd1 = (const float*)d_in[17];
    const float* wd2 = (const float*)d_in[18], *bd2 = (const float*)d_in[19];
    const float* wn  = (const float*)d_in[20], *bn  = (const float*)d_in[21];
    const float* we  = (const float*)d_in[22], *be  = (const float*)d_in[23];

    float* out = (float*)d_out;
    float* out_adj = out;                                                  // 2,560,000
    float* out_nf  = out + (long)NUM_GRAPHS * MAX_NODES * MAX_NODES;       // 409,600
    float* out_mu  = out_nf + (long)NUM_GRAPHS * MAX_NODES * NODE_DIM;     // 16,384
    float* out_lv  = out_mu + NUM_GRAPHS * LATENT;                         // 16,384

    float* ws = (float*)d_ws;
    ushort_t* h1 = (ushort_t*)ws;                     // 6.4M bf16 = 3.2M floats
    float* summed = ws + 3200000;                     // 32,768
    float* hd     = summed + NUM_GRAPHS * HIDDEN;     // 32,768
    int*   deg       = (int*)(hd + NUM_GRAPHS * HIDDEN);
    int*   row_start = deg + N_NODES;                 // 50,001 ints
    int*   cursor    = row_start + N_NODES + 1;       // 50,000 ints
    int*   nbr       = cursor + N_NODES;              // 640,000 ints
    int*   blocksum  = nbr + N_EDGES;                 // 49 ints
    ushort_t* wpk1b = (ushort_t*)(((uintptr_t)(blocksum + 64) + 15) & ~(uintptr_t)15);
    ushort_t* wpk2a = wpk1b + HIDDEN * HIDDEN;        // 16,384 each
    ushort_t* wpk2b = wpk2a + HIDDEN * HIDDEN;
    // raw decoder buffers reuse the h1 region (dead after gin2): 2.97M < 3.2M
    float* raw_adj = (float*)h1;
    float* raw_nf  = (float*)h1 + (long)NUM_GRAPHS * MAX_NODES * MAX_NODES;

    // ---- CSR build + weight pack ----
    hipMemsetAsync(deg, 0, sizeof(int) * N_NODES, stream);
    degree_kernel<<<N_EDGES / 4 / 256, 256, 0, stream>>>(dst, deg);
    blockscan_kernel<<<(N_NODES + 1023) / 1024, 1024, 0, stream>>>(deg, row_start, blocksum);
    scan_fixup_kernel<<<(N_NODES + 1023) / 1024, 1024, 0, stream>>>(row_start, cursor,
                                                                    blocksum, summed);
    csr_fill_kernel<<<N_EDGES / 4 / 256, 256, 0, stream>>>(src, dst, cursor, nbr);
    pack_w3_kernel<<<192, 256, 0, stream>>>(w1b, wpk1b, w2a, wpk2a, w2b, wpk2b);

    // ---- GIN layers (gin2 fuses the mean-pool partials) ----
    gin1_fused_kernel<<<N_NODES / 16, 128, 0, stream>>>(x, row_start, nbr,
                                                        w1a, b1a, wpk1b, b1b, h1);
    gin2_fused_kernel<<<N_NODES / 16, 128, 0, stream>>>(h1, row_start, nbr, batch,
                                                        wpk2a, b2a, wpk2b, b2b, summed);

    // ---- heads + reparam + decoder trunk ----
    head_kernel<<<NUM_GRAPHS, 128, 0, stream>>>(summed, batch, eps,
                                                wmu, bmu, wlv, blv,
                                                wd1, bd1, wd2, bd2,
                                                out_mu, out_lv, hd);

    // ---- decoder GEMMs (merged, GB=16, 8-deep prefetch) ----
    {
        dim3 grid(ADJ_BLOCKS + 7, NUM_GRAPHS / GB2);   // 47 x 16 = 752 blocks
        decoder_gemm2_kernel<<<grid, 256, 0, stream>>>(hd, we, be, raw_adj,
                                                       wn, bn, raw_nf);
    }

    // ---- merged epilogue: adj sym/clip + nf softmax ----
    epilogue_kernel<<<NUM_GRAPHS + 50, 512, 0, stream>>>(raw_adj, out_adj,
                                                         raw_nf, out_nf);
}

// Round 16
// 184.827 us; speedup vs baseline: 1.1090x; 1.0086x over previous
//
#include <hip/hip_runtime.h>
#include <hip/hip_bf16.h>

#define N_NODES   50000
#define N_EDGES   640000
#define NODE_DIM  16
#define HIDDEN    128
#define LATENT    64
#define MAX_NODES 100
#define NUM_GRAPHS 256

typedef unsigned short ushort_t;
typedef unsigned int   uint_t;
typedef short  short8 __attribute__((ext_vector_type(8)));   // 8 bf16 = 4 VGPR
typedef float  f32x4  __attribute__((ext_vector_type(4)));

__device__ __forceinline__ float bf2f(ushort_t u) {
    return __uint_as_float(((uint_t)u) << 16);
}
__device__ __forceinline__ ushort_t f2bf(float f) {
    const uint_t u = __float_as_uint(f);
    return (ushort_t)((u + 0x7fffu + ((u >> 16) & 1u)) >> 16);   // RNE
}

// MFMA 16x16x32 bf16 via inline asm. D=C tied ("+v").
//   A[m][k]: m = lane&15, k = (lane>>4)*8 + j
//   B[k][n]: n = lane&15, k = (lane>>4)*8 + j
//   D[m][n]: n = lane&15, m = (lane>>4)*4 + r
// NOTE (round 11): porting this to the decoder GEMM produced absmax 1.99
// (structural). Decoder stays fp32-VALU; MFMA only in gin kernels (proven).
__device__ __forceinline__ void mfma_acc(f32x4& acc, short8 a, short8 b) {
    asm volatile("v_mfma_f32_16x16x32_bf16 %0, %1, %2, %0"
                 : "+v"(acc) : "v"(a), "v"(b));
}
__device__ __forceinline__ void mfma_hazard_wait() {
    asm volatile("s_nop 7\n\ts_nop 7");
}

// ===========================================================================
// CSR build (by dst). 8 edges/thread (round 16; round 9 showed per-thread
// independent atomic round-trips are the lever: 62ns/op serial -> overlapped).
// ===========================================================================
__global__ void degree_kernel(const int* __restrict__ dst, int* __restrict__ deg) {
    const int i0 = (blockIdx.x * blockDim.x + threadIdx.x) * 8;
    if (i0 + 8 <= N_EDGES) {
        const int4 d0 = *(const int4*)&dst[i0];
        const int4 d1 = *(const int4*)&dst[i0 + 4];
        atomicAdd(&deg[d0.x], 1); atomicAdd(&deg[d0.y], 1);
        atomicAdd(&deg[d0.z], 1); atomicAdd(&deg[d0.w], 1);
        atomicAdd(&deg[d1.x], 1); atomicAdd(&deg[d1.y], 1);
        atomicAdd(&deg[d1.z], 1); atomicAdd(&deg[d1.w], 1);
    }
}

// Combined: blocks [0,49) = block-local exclusive scan; blocks [49,97) =
// GIN weight pack (independent work, one launch saved).
__global__ void blockscan_pack_kernel(const int* __restrict__ deg,
                                      int* __restrict__ row_start,
                                      int* __restrict__ blocksum,
                                      const float* __restrict__ wA, ushort_t* __restrict__ oA,
                                      const float* __restrict__ wB, ushort_t* __restrict__ oB,
                                      const float* __restrict__ wC, ushort_t* __restrict__ oC) {
    const int tid = threadIdx.x;
    if (blockIdx.x >= 49) {   // ---- pack role ----
        const int gid = (blockIdx.x - 49) * 1024 + tid;   // [0, 49152)
        const int sel = gid >> 14;
        const int idx = gid & 16383;
        const float* w = (sel == 0) ? wA : (sel == 1) ? wB : wC;
        ushort_t* out  = (sel == 0) ? oA : (sel == 1) ? oB : oC;
        const int j    = idx & 7;
        const int lane = (idx >> 3) & 63;
        const int kb   = (idx >> 9) & 3;
        const int nt   = idx >> 11;
        const int k = kb * 32 + ((lane >> 4) << 3) + j;
        const int n = (nt << 4) + (lane & 15);
        out[idx] = f2bf(w[k * HIDDEN + n]);
        return;
    }
    // ---- scan role ----
    __shared__ int s_wave[16];
    const int lane = tid & 63;
    const int wid  = tid >> 6;
    const int idx  = blockIdx.x * 1024 + tid;

    const int v = (idx < N_NODES) ? deg[idx] : 0;
    int x = v;
    #pragma unroll
    for (int o = 1; o < 64; o <<= 1) {
        const int y = __shfl_up(x, o);
        if (lane >= o) x += y;
    }
    if (lane == 63) s_wave[wid] = x;
    __syncthreads();
    if (tid == 0) {
        int run = 0;
        #pragma unroll
        for (int w = 0; w < 16; ++w) { const int t = s_wave[w]; s_wave[w] = run; run += t; }
        blocksum[blockIdx.x] = run;
    }
    __syncthreads();
    if (idx < N_NODES) row_start[idx] = s_wave[wid] + x - v;
}

// Stage 2: add prefix of blocksums; write cursor; zero `summed` (fused:
// runs before gin2, which accumulates pool partials into summed).
__global__ void scan_fixup_kernel(int* __restrict__ row_start,
                                  int* __restrict__ cursor,
                                  const int* __restrict__ blocksum,
                                  float* __restrict__ summed) {
    __shared__ int s_off;
    const int bid = blockIdx.x;
    const int tid = threadIdx.x;
    if (tid < 64) {
        int v = (tid < bid) ? blocksum[tid] : 0;
        #pragma unroll
        for (int o = 32; o > 0; o >>= 1) v += __shfl_down(v, o);
        if (tid == 0) s_off = v;
    }
    __syncthreads();
    const int idx = bid * 1024 + tid;
    if (idx < N_NODES) {
        const int r = row_start[idx] + s_off;
        row_start[idx] = r;
        cursor[idx] = r;
    }
    if (idx < NUM_GRAPHS * HIDDEN) summed[idx] = 0.f;
    if (bid == 0 && tid == 0) row_start[N_NODES] = N_EDGES;
}

__global__ void csr_fill_kernel(const int* __restrict__ src,
                                const int* __restrict__ dst,
                                int* __restrict__ cursor,
                                int* __restrict__ nbr) {
    const int i0 = (blockIdx.x * blockDim.x + threadIdx.x) * 8;
    if (i0 + 8 <= N_EDGES) {
        const int4 d0 = *(const int4*)&dst[i0];
        const int4 d1 = *(const int4*)&dst[i0 + 4];
        const int4 s0 = *(const int4*)&src[i0];
        const int4 s1 = *(const int4*)&src[i0 + 4];
        const int p0 = atomicAdd(&cursor[d0.x], 1);
        const int p1 = atomicAdd(&cursor[d0.y], 1);
        const int p2 = atomicAdd(&cursor[d0.z], 1);
        const int p3 = atomicAdd(&cursor[d0.w], 1);
        const int p4 = atomicAdd(&cursor[d1.x], 1);
        const int p5 = atomicAdd(&cursor[d1.y], 1);
        const int p6 = atomicAdd(&cursor[d1.z], 1);
        const int p7 = atomicAdd(&cursor[d1.w], 1);
        nbr[p0] = s0.x; nbr[p1] = s0.y; nbr[p2] = s0.z; nbr[p3] = s0.w;
        nbr[p4] = s1.x; nbr[p5] = s1.y; nbr[p6] = s1.z; nbr[p7] = s1.w;
    }
}

// ===========================================================================
// Fused GIN layer 1: gather(x,16) + VALU MLP-A(16->128) + MFMA MLP-B.
// ===========================================================================
__global__ void gin1_fused_kernel(const float* __restrict__ in,
                                  const int* __restrict__ row_start,
                                  const int* __restrict__ nbr,
                                  const float* __restrict__ wa, const float* __restrict__ ba,
                                  const ushort_t* __restrict__ wpkb, const float* __restrict__ bb,
                                  ushort_t* __restrict__ out) {
    __shared__ float s_in[16][NODE_DIM + 1];                 // stride 17
    __shared__ __align__(16) ushort_t s_mid[16][HIDDEN + 8]; // bf16, stride 136
    const int tid = threadIdx.x;
    const int n0  = blockIdx.x * 16;

    {   // gather: 8 groups x 16 dims, 2 nodes/group, 4-acc ILP
        const int grp = tid >> 4;
        const int k   = tid & 15;
        #pragma unroll
        for (int half = 0; half < 2; ++half) {
            const int i = grp + half * 8;
            const int n = n0 + i;
            const int beg = row_start[n], end = row_start[n + 1];
            float a0 = in[(long)n * NODE_DIM + k], a1 = 0.f, a2 = 0.f, a3 = 0.f;
            int p = beg;
            for (; p + 4 <= end; p += 4) {
                const int e0 = nbr[p], e1 = nbr[p + 1], e2 = nbr[p + 2], e3 = nbr[p + 3];
                a0 += in[(long)e0 * NODE_DIM + k];
                a1 += in[(long)e1 * NODE_DIM + k];
                a2 += in[(long)e2 * NODE_DIM + k];
                a3 += in[(long)e3 * NODE_DIM + k];
            }
            for (; p < end; ++p) a0 += in[(long)nbr[p] * NODE_DIM + k];
            s_in[i][k] = (a0 + a1) + (a2 + a3);
        }
    }
    __syncthreads();

    {   // layer A (K=16), VALU 4x4 tile, write s_mid bf16
        const int dq = tid & 31;  const int d0 = dq * 4;
        const int iq = tid >> 5;  const int i0 = iq * 4;
        float acc[4][4];
        const float4 bv = *(const float4*)&ba[d0];
        #pragma unroll
        for (int j = 0; j < 4; ++j) {
            acc[j][0] = bv.x; acc[j][1] = bv.y; acc[j][2] = bv.z; acc[j][3] = bv.w;
        }
        for (int k = 0; k < NODE_DIM; ++k) {
            const float4 w = *(const float4*)&wa[k * HIDDEN + d0];
            #pragma unroll
            for (int j = 0; j < 4; ++j) {
                const float a = s_in[i0 + j][k];
                acc[j][0] += a * w.x; acc[j][1] += a * w.y;
                acc[j][2] += a * w.z; acc[j][3] += a * w.w;
            }
        }
        #pragma unroll
        for (int j = 0; j < 4; ++j) {
            ushort4 v;
            v.x = f2bf(fmaxf(acc[j][0], 0.f)); v.y = f2bf(fmaxf(acc[j][1], 0.f));
            v.z = f2bf(fmaxf(acc[j][2], 0.f)); v.w = f2bf(fmaxf(acc[j][3], 0.f));
            *(ushort4*)&s_mid[i0 + j][d0] = v;
        }
    }
    __syncthreads();

    {   // layer B (K=128) on MFMA -> h1 bf16
        const int lane = tid & 63;
        const int wv   = tid >> 6;
        short8 afr[4];
        #pragma unroll
        for (int kb = 0; kb < 4; ++kb)
            afr[kb] = *(const short8*)&s_mid[lane & 15][kb * 32 + ((lane >> 4) << 3)];
        const int col = lane & 15;
        const int r0  = (lane >> 4) << 2;
        #pragma unroll
        for (int t = 0; t < 4; ++t) {
            const int nt = wv * 4 + t;
            short8 bfr[4];
            #pragma unroll
            for (int kb = 0; kb < 4; ++kb)
                bfr[kb] = *(const short8*)&wpkb[(((nt << 2) | kb) << 9) + (lane << 3)];
            f32x4 acc = {0.f, 0.f, 0.f, 0.f};
            #pragma unroll
            for (int kb = 0; kb < 4; ++kb) mfma_acc(acc, afr[kb], bfr[kb]);
            mfma_hazard_wait();
            const float bias = bb[nt * 16 + col];
            #pragma unroll
            for (int r = 0; r < 4; ++r)
                out[(long)(n0 + r0 + r) * HIDDEN + nt * 16 + col] =
                    f2bf(fmaxf(acc[r] + bias, 0.f));
        }
    }
}

// ===========================================================================
// Fused GIN layer 2 + POOL: gather(h1 bf16) + MFMA MLP A/B; layer-B output
// stays in LDS (s_h2 OVERLAYS s_in/s_mid, stride 132 = free 2-way aliasing)
// and is run-length pooled into `summed`. (Round 15 proven: 12.8KB LDS,
// occupancy ~43%, bank conflicts eliminated.)
// ===========================================================================
__global__ void gin2_fused_kernel(const ushort_t* __restrict__ in,
                                  const int* __restrict__ row_start,
                                  const int* __restrict__ nbr,
                                  const int* __restrict__ batch,
                                  const ushort_t* __restrict__ wpka, const float* __restrict__ ba,
                                  const ushort_t* __restrict__ wpkb, const float* __restrict__ bb,
                                  float* __restrict__ summed) {
    __shared__ __align__(16) ushort_t s_buf[2][16][HIDDEN + 8];
    __shared__ int s_b[16];
    float (*s_h2)[HIDDEN + 4] = (float(*)[HIDDEN + 4]) & s_buf[0][0][0];
    const int tid  = threadIdx.x;
    const int lane = tid & 63;
    const int wv   = tid >> 6;                 // 0..1
    const int n0   = blockIdx.x * 16;

    if (tid < 16) s_b[tid] = batch[n0 + tid];

    {   // gather: wave wv -> nodes wv*8..wv*8+7, lane = bf16 pair, 8-acc ILP
        const int d2 = lane * 2;
        #pragma unroll
        for (int t = 0; t < 8; ++t) {
            const int i = wv * 8 + t;
            const int n = n0 + i;
            const int beg = row_start[n], end = row_start[n + 1];
            const uint_t sv = *(const uint_t*)&in[(long)n * HIDDEN + d2];
            float ax[8], ay[8];
            ax[0] = bf2f(sv & 0xffffu); ay[0] = bf2f(sv >> 16);
            #pragma unroll
            for (int q = 1; q < 8; ++q) { ax[q] = 0.f; ay[q] = 0.f; }
            int p = beg;
            for (; p + 8 <= end; p += 8) {
                uint_t v[8];
                #pragma unroll
                for (int q = 0; q < 8; ++q)
                    v[q] = *(const uint_t*)&in[(long)nbr[p + q] * HIDDEN + d2];
                #pragma unroll
                for (int q = 0; q < 8; ++q) {
                    ax[q] += bf2f(v[q] & 0xffffu); ay[q] += bf2f(v[q] >> 16);
                }
            }
            for (; p + 2 <= end; p += 2) {
                const uint_t v0 = *(const uint_t*)&in[(long)nbr[p]     * HIDDEN + d2];
                const uint_t v1 = *(const uint_t*)&in[(long)nbr[p + 1] * HIDDEN + d2];
                ax[0] += bf2f(v0 & 0xffffu); ay[0] += bf2f(v0 >> 16);
                ax[1] += bf2f(v1 & 0xffffu); ay[1] += bf2f(v1 >> 16);
            }
            if (p < end) {
                const uint_t v0 = *(const uint_t*)&in[(long)nbr[p] * HIDDEN + d2];
                ax[0] += bf2f(v0 & 0xffffu); ay[0] += bf2f(v0 >> 16);
            }
            const float rx = ((ax[0] + ax[1]) + (ax[2] + ax[3])) + ((ax[4] + ax[5]) + (ax[6] + ax[7]));
            const float ry = ((ay[0] + ay[1]) + (ay[2] + ay[3])) + ((ay[4] + ay[5]) + (ay[6] + ay[7]));
            const uint_t packed = (uint_t)f2bf(rx) | ((uint_t)f2bf(ry) << 16);
            *(uint_t*)&s_buf[0][i][d2] = packed;
        }
    }
    __syncthreads();

    const int col = lane & 15;
    const int r0  = (lane >> 4) << 2;

    {   // layer A (K=128) on MFMA -> s_mid bf16
        short8 afr[4];
        #pragma unroll
        for (int kb = 0; kb < 4; ++kb)
            afr[kb] = *(const short8*)&s_buf[0][lane & 15][kb * 32 + ((lane >> 4) << 3)];
        #pragma unroll
        for (int t = 0; t < 4; ++t) {
            const int nt = wv * 4 + t;
            short8 bfr[4];
            #pragma unroll
            for (int kb = 0; kb < 4; ++kb)
                bfr[kb] = *(const short8*)&wpka[(((nt << 2) | kb) << 9) + (lane << 3)];
            f32x4 acc = {0.f, 0.f, 0.f, 0.f};
            #pragma unroll
            for (int kb = 0; kb < 4; ++kb) mfma_acc(acc, afr[kb], bfr[kb]);
            mfma_hazard_wait();
            const float bias = ba[nt * 16 + col];
            #pragma unroll
            for (int r = 0; r < 4; ++r)
                s_buf[1][r0 + r][nt * 16 + col] = f2bf(fmaxf(acc[r] + bias, 0.f));
        }
    }
    __syncthreads();

    {   // layer B (K=128) on MFMA -> s_h2 (overlays s_in/s_mid)
        short8 afr[4];
        #pragma unroll
        for (int kb = 0; kb < 4; ++kb)
            afr[kb] = *(const short8*)&s_buf[1][lane & 15][kb * 32 + ((lane >> 4) << 3)];
        __syncthreads();   // all waves hold fragments; s_in/s_mid now dead
        #pragma unroll
        for (int t = 0; t < 4; ++t) {
            const int nt = wv * 4 + t;
            short8 bfr[4];
            #pragma unroll
            for (int kb = 0; kb < 4; ++kb)
                bfr[kb] = *(const short8*)&wpkb[(((nt << 2) | kb) << 9) + (lane << 3)];
            f32x4 acc = {0.f, 0.f, 0.f, 0.f};
            #pragma unroll
            for (int kb = 0; kb < 4; ++kb) mfma_acc(acc, afr[kb], bfr[kb]);
            mfma_hazard_wait();
            const float bias = bb[nt * 16 + col];
            #pragma unroll
            for (int r = 0; r < 4; ++r)
                s_h2[r0 + r][nt * 16 + col] = fmaxf(acc[r] + bias, 0.f);
        }
    }
    __syncthreads();

    {   // fused mean-pool partial: run-length over the 16 sorted nodes
        const int d = tid & 127;
        int cur = s_b[0];
        float acc = 0.f;
        #pragma unroll
        for (int i = 0; i < 16; ++i) {
            const int g = s_b[i];
            if (g != cur) {
                atomicAdd(&summed[cur * HIDDEN + d], acc);
                acc = 0.f; cur = g;
            }
            acc += s_h2[i][d];
        }
        atomicAdd(&summed[cur * HIDDEN + d], acc);
    }
}

// ---------------------------------------------------------------------------
// Per-graph head: pooled -> mu, logvar, z -> hd. Counts via binary search on
// the sorted batch array.
// ---------------------------------------------------------------------------
__global__ void head_kernel(const float* __restrict__ summed,
                            const int* __restrict__ batch,
                            const float* __restrict__ eps,
                            const float* __restrict__ wmu, const float* __restrict__ bmu,
                            const float* __restrict__ wlv, const float* __restrict__ blv,
                            const float* __restrict__ wd1, const float* __restrict__ bd1,
                            const float* __restrict__ wd2, const float* __restrict__ bd2,
                            float* __restrict__ out_mu, float* __restrict__ out_lv,
                            float* __restrict__ hd) {
    const int g = blockIdx.x;
    const int d = threadIdx.x;
    __shared__ float s_pool[HIDDEN];
    __shared__ float s_z[LATENT];
    __shared__ float s_h1[HIDDEN];
    __shared__ float s_cnt;

    if (d == 0) {
        int lo = 0, hi = N_NODES;
        while (lo < hi) { const int m = (lo + hi) >> 1; if (batch[m] < g) lo = m + 1; else hi = m; }
        int lo2 = lo, hi2 = N_NODES;
        while (lo2 < hi2) { const int m = (lo2 + hi2) >> 1; if (batch[m] < g + 1) lo2 = m + 1; else hi2 = m; }
        s_cnt = fmaxf((float)(lo2 - lo), 1.f);
    }
    __syncthreads();
    s_pool[d] = summed[g * HIDDEN + d] / s_cnt;
    __syncthreads();

    if (d < LATENT) {
        float m = bmu[d], lv = blv[d];
        for (int k = 0; k < HIDDEN; ++k) {
            const float p = s_pool[k];
            m  += p * wmu[k * LATENT + d];
            lv += p * wlv[k * LATENT + d];
        }
        lv = fminf(fmaxf(lv, -5.f), 5.f);
        out_mu[g * LATENT + d] = m;
        out_lv[g * LATENT + d] = lv;
        s_z[d] = m + eps[g * LATENT + d] * expf(0.5f * lv);
    }
    __syncthreads();
    {
        float a = bd1[d];
        for (int k = 0; k < LATENT; ++k) a += s_z[k] * wd1[k * HIDDEN + d];
        s_h1[d] = fmaxf(a, 0.f);
    }
    __syncthreads();
    {
        float a = bd2[d];
        for (int k = 0; k < HIDDEN; ++k) a += s_h1[k] * wd2[k * HIDDEN + d];
        hd[g * HIDDEN + d] = a;
    }
}

// ---------------------------------------------------------------------------
// Decoder GEMM (merged adj+nf), fp32. GB=16 (752 blocks) + float4 W loads +
// 4-col threads + manual 8-deep W prefetch (round 13 proven).
// ---------------------------------------------------------------------------
#define GB2 16
#define ADJ_BLOCKS 40   // ceil(10000/256)
__global__ void decoder_gemm2_kernel(const float* __restrict__ hd,
                                     const float* __restrict__ we, const float* __restrict__ be,
                                     float* __restrict__ raw_adj,
                                     const float* __restrict__ wn, const float* __restrict__ bn,
                                     float* __restrict__ raw_nf) {
    const int g0 = blockIdx.y * GB2;
    const bool is_adj = (blockIdx.x < ADJ_BLOCKS);
    const float* W    = is_adj ? we : wn;
    const float* bias = is_adj ? be : bn;
    float* raw        = is_adj ? raw_adj : raw_nf;
    const int N       = is_adj ? (MAX_NODES * MAX_NODES) : (MAX_NODES * NODE_DIM);
    const int bx      = is_adj ? blockIdx.x : blockIdx.x - ADJ_BLOCKS;
    const int cg = threadIdx.x & 63;    // column group: 4 cols
    const int gg = threadIdx.x >> 6;    // graph group: 4 graphs
    const int o0 = bx * 256 + cg * 4;

    __shared__ float s_hd[GB2][HIDDEN]; // 8KB
    for (int idx = threadIdx.x; idx < GB2 * HIDDEN; idx += 256) {
        s_hd[idx >> 7][idx & 127] = hd[(long)(g0 + (idx >> 7)) * HIDDEN + (idx & 127)];
    }
    __syncthreads();
    if (o0 >= N) return;   // safe: no barriers after this point

    float4 acc[4];
    const float4 bv = *(const float4*)&bias[o0];
    #pragma unroll
    for (int j = 0; j < 4; ++j) acc[j] = bv;

    for (int k0 = 0; k0 < HIDDEN; k0 += 8) {
        float4 w[8];
        #pragma unroll
        for (int u = 0; u < 8; ++u)
            w[u] = *(const float4*)&W[(long)(k0 + u) * N + o0];
        #pragma unroll
        for (int u = 0; u < 8; ++u) {
            #pragma unroll
            for (int j = 0; j < 4; ++j) {
                const float a = s_hd[gg * 4 + j][k0 + u];   // wave-uniform broadcast
                acc[j].x += a * w[u].x; acc[j].y += a * w[u].y;
                acc[j].z += a * w[u].z; acc[j].w += a * w[u].w;
            }
        }
    }
    #pragma unroll
    for (int j = 0; j < 4; ++j)
        *(float4*)&raw[(long)(g0 + gg * 4 + j) * N + o0] = acc[j];
}

// ---------------------------------------------------------------------------
// Merged epilogue: blocks [0,256) = adj symmetrize/clip; [256,306) = softmax.
// ---------------------------------------------------------------------------
__global__ void epilogue_kernel(const float* __restrict__ raw_adj,
                                float* __restrict__ out_adj,
                                const float* __restrict__ raw_nf,
                                float* __restrict__ out_nf) {
    const int tid = threadIdx.x;
    if (blockIdx.x < NUM_GRAPHS) {
        const int g = blockIdx.x;
        __shared__ float s_a[MAX_NODES * MAX_NODES];
        const float* r = raw_adj + (long)g * MAX_NODES * MAX_NODES;
        for (int o = tid; o < MAX_NODES * MAX_NODES; o += blockDim.x) s_a[o] = r[o];
        __syncthreads();
        float* w = out_adj + (long)g * MAX_NODES * MAX_NODES;
        for (int o = tid; o < MAX_NODES * MAX_NODES; o += blockDim.x) {
            const int i = o / MAX_NODES;
            const int j = o - i * MAX_NODES;
            float v;
            if (i == j) v = -10.f;
            else        v = fminf(fmaxf(0.5f * (s_a[o] + s_a[j * MAX_NODES + i]), -10.f), 10.f);
            w[o] = v;
        }
    } else {
        const int idx = (blockIdx.x - NUM_GRAPHS) * blockDim.x + tid;  // (g,m)
        if (idx >= NUM_GRAPHS * MAX_NODES) return;
        const float* r = raw_nf + (long)idx * NODE_DIM;
        float mx = -1e30f;
        #pragma unroll
        for (int d = 0; d < NODE_DIM; ++d) mx = fmaxf(mx, r[d]);
        float e[NODE_DIM];
        float s = 0.f;
        #pragma unroll
        for (int d = 0; d < NODE_DIM; ++d) { e[d] = expf(r[d] - mx); s += e[d]; }
        const float inv = 1.f / s;
        float* w = out_nf + (long)idx * NODE_DIM;
        #pragma unroll
        for (int d = 0; d < NODE_DIM; ++d) w[d] = e[d] * inv;
    }
}

// ---------------------------------------------------------------------------
extern "C" void kernel_launch(void* const* d_in, const int* in_sizes, int n_in,
                              void* d_out, int out_size, void* d_ws, size_t ws_size,
                              hipStream_t stream) {
    const float* x    = (const float*)d_in[0];
    const int*   edge = (const int*)d_in[1];
    const int*   src  = edge;
    const int*   dst  = edge + N_EDGES;
    const int*   batch = (const int*)d_in[2];
    const float* eps  = (const float*)d_in[3];
    const float* w1a = (const float*)d_in[4],  *b1a = (const float*)d_in[5];
    const float* w1b = (const float*)d_in[6],  *b1b = (const float*)d_in[7];
    const float* w2a = (const float*)d_in[8],  *b2a = (const float*)d_in[9];
    const float* w2b = (const float*)d_in[10], *b2b = (const float*)d_in[11];
    const float* wmu = (const float*)d_in[12], *bmu = (const float*)d_in[13];
    const float* wlv = (const float*)d_in[14], *blv = (const float*)d_in[15];
    const float* wd1 = (const float*)d_in[16], *bd1 = (const float*)d_in[17];
    const float* wd2 = (const float*)d_in[18], *bd2 = (const float*)d_in[19];
    const float* wn  = (const float*)d_in[20], *bn  = (const float*)d_in[21];
    const float* we  = (const float*)d_in[22], *be  = (const float*)d_in[23];

    float* out = (float*)d_out;
    float* out_adj = out;                                                  // 2,560,000
    float* out_nf  = out + (long)NUM_GRAPHS * MAX_NODES * MAX_NODES;       // 409,600
    float* out_mu  = out_nf + (long)NUM_GRAPHS * MAX_NODES * NODE_DIM;     // 16,384
    float* out_lv  = out_mu + NUM_GRAPHS * LATENT;                         // 16,384

    float* ws = (float*)d_ws;
    ushort_t* h1 = (ushort_t*)ws;                     // 6.4M bf16 = 3.2M floats
    float* summed = ws + 3200000;                     // 32,768
    float* hd     = summed + NUM_GRAPHS * HIDDEN;     // 32,768
    int*   deg       = (int*)(hd + NUM_GRAPHS * HIDDEN);
    int*   row_start = deg + N_NODES;                 // 50,001 ints
    int*   cursor    = row_start + N_NODES + 1;       // 50,000 ints
    int*   nbr       = cursor + N_NODES;              // 640,000 ints
    int*   blocksum  = nbr + N_EDGES;                 // 49 ints
    ushort_t* wpk1b = (ushort_t*)(((uintptr_t)(blocksum + 64) + 15) & ~(uintptr_t)15);
    ushort_t* wpk2a = wpk1b + HIDDEN * HIDDEN;        // 16,384 each
    ushort_t* wpk2b = wpk2a + HIDDEN * HIDDEN;
    // raw decoder buffers reuse the h1 region (dead after gin2): 2.97M < 3.2M
    float* raw_adj = (float*)h1;
    float* raw_nf  = (float*)h1 + (long)NUM_GRAPHS * MAX_NODES * MAX_NODES;

    // ---- CSR build + weight pack (pack merged into blockscan launch) ----
    hipMemsetAsync(deg, 0, sizeof(int) * N_NODES, stream);
    degree_kernel<<<(N_EDGES / 8 + 255) / 256, 256, 0, stream>>>(dst, deg);
    blockscan_pack_kernel<<<49 + 48, 1024, 0, stream>>>(deg, row_start, blocksum,
                                                        w1b, wpk1b, w2a, wpk2a, w2b, wpk2b);
    scan_fixup_kernel<<<(N_NODES + 1023) / 1024, 1024, 0, stream>>>(row_start, cursor,
                                                                    blocksum, summed);
    csr_fill_kernel<<<(N_EDGES / 8 + 255) / 256, 256, 0, stream>>>(src, dst, cursor, nbr);

    // ---- GIN layers (gin2 fuses the mean-pool partials) ----
    gin1_fused_kernel<<<N_NODES / 16, 128, 0, stream>>>(x, row_start, nbr,
                                                        w1a, b1a, wpk1b, b1b, h1);
    gin2_fused_kernel<<<N_NODES / 16, 128, 0, stream>>>(h1, row_start, nbr, batch,
                                                        wpk2a, b2a, wpk2b, b2b, summed);

    // ---- heads + reparam + decoder trunk ----
    head_kernel<<<NUM_GRAPHS, 128, 0, stream>>>(summed, batch, eps,
                                                wmu, bmu, wlv, blv,
                                                wd1, bd1, wd2, bd2,
                                                out_mu, out_lv, hd);

    // ---- decoder GEMMs (merged, GB=16, 8-deep prefetch) ----
    {
        dim3 grid(ADJ_BLOCKS + 7, NUM_GRAPHS / GB2);   // 47 x 16 = 752 blocks
        decoder_gemm2_kernel<<<grid, 256, 0, stream>>>(hd, we, be, raw_adj,
                                                       wn, bn, raw_nf);
    }

    // ---- merged epilogue: adj sym/clip + nf softmax ----
    epilogue_kernel<<<NUM_GRAPHS + 50, 512, 0, stream>>>(raw_adj, out_adj,
                                                         raw_nf, out_nf);
}